// Round 1
// baseline (515.548 us; speedup 1.0000x reference)
//
#include <hip/hip_runtime.h>
#include <math.h>

#define BATCH     1024
#define TEXT_LEN  512
#define NUM_CAND  31
#define DIM       256

// One block per batch row. 256 threads = 4 waves.
// Phase 1: masked gather-sum of word embeddings (each wave reads full 1KB rows as float4).
// Phase 2: L2 normalize (block reduction).
// Phase 3: t = vec @ W + b (thread d owns output dim d; coalesced column reads of W).
// Phase 4: 31 candidate dot products (wave-parallel, shuffle reduce).
// Phase 5: softmax over 31 (single wave).
__global__ __launch_bounds__(256) void ntee_fused(
    const float* __restrict__ word_emb,
    const float* __restrict__ entity_emb,
    const float* __restrict__ W,
    const float* __restrict__ bias,
    const int*   __restrict__ text_input,
    const int*   __restrict__ entity_input,
    float*       __restrict__ out)
{
    const int b    = blockIdx.x;
    const int tid  = threadIdx.x;
    const int lane = tid & 63;   // lane within wave
    const int grp  = tid >> 6;   // wave id (0..3)

    __shared__ int   idx_lds[TEXT_LEN];   // 2 KB
    __shared__ float red[4][DIM];         // 4 KB cross-wave partials
    __shared__ float vec_lds[DIM];        // 1 KB normalized vec
    __shared__ float t_lds[DIM];          // 1 KB affine output
    __shared__ int   ent_lds[NUM_CAND];
    __shared__ float sim_lds[NUM_CAND];
    __shared__ float wsum[4];

    // ---- load indices into LDS (coalesced) ----
    for (int i = tid; i < TEXT_LEN; i += 256)
        idx_lds[i] = text_input[b * TEXT_LEN + i];
    if (tid < NUM_CAND)
        ent_lds[tid] = entity_input[b * NUM_CAND + tid];
    __syncthreads();

    // ---- Phase 1: masked gather-sum ----
    // Wave `grp` handles tokens l = grp, grp+4, ... Each lane reads 16B of the
    // 1KB row -> one fully-coalesced 1KB request per wave per token.
    float4 acc = make_float4(0.f, 0.f, 0.f, 0.f);
    #pragma unroll 4
    for (int l = grp; l < TEXT_LEN; l += 4) {
        const int idx = idx_lds[l];          // uniform within the wave
        if (idx != 0) {
            const float4 v = *reinterpret_cast<const float4*>(
                &word_emb[(size_t)idx * DIM + lane * 4]);
            acc.x += v.x; acc.y += v.y; acc.z += v.z; acc.w += v.w;
        }
    }
    *reinterpret_cast<float4*>(&red[grp][lane * 4]) = acc;
    __syncthreads();

    // thread tid owns dim d = tid
    float v = red[0][tid] + red[1][tid] + red[2][tid] + red[3][tid];

    // ---- Phase 2: L2 norm ----
    float sq = v * v;
    #pragma unroll
    for (int off = 32; off; off >>= 1) sq += __shfl_xor(sq, off);
    if (lane == 0) wsum[grp] = sq;
    __syncthreads();
    const float total = wsum[0] + wsum[1] + wsum[2] + wsum[3];
    const float inv   = 1.0f / sqrtf(total);
    vec_lds[tid] = v * inv;
    __syncthreads();

    // ---- Phase 3: t = vec @ W + b ----
    // t[d] = b[d] + sum_i vec[i] * W[i*DIM + d]; column reads are coalesced.
    float t = bias[tid];
    #pragma unroll 8
    for (int i = 0; i < DIM; ++i)
        t = fmaf(vec_lds[i], W[i * DIM + tid], t);
    t_lds[tid] = t;
    __syncthreads();

    // ---- Phase 4: candidate dot products ----
    const float4 tt = *reinterpret_cast<const float4*>(&t_lds[lane * 4]);
    for (int k = grp; k < NUM_CAND; k += 4) {
        const int eid = ent_lds[k];          // uniform within the wave
        const float4 e = *reinterpret_cast<const float4*>(
            &entity_emb[(size_t)eid * DIM + lane * 4]);
        float p = e.x * tt.x + e.y * tt.y + e.z * tt.z + e.w * tt.w;
        #pragma unroll
        for (int off = 32; off; off >>= 1) p += __shfl_xor(p, off);
        if (lane == 0) sim_lds[k] = p;
    }
    __syncthreads();

    // ---- Phase 5: softmax over 31 candidates (wave 0 only) ----
    if (grp == 0) {
        const float s = (lane < NUM_CAND) ? sim_lds[lane] : -INFINITY;
        float m = s;
        #pragma unroll
        for (int off = 32; off; off >>= 1) m = fmaxf(m, __shfl_xor(m, off));
        const float e = (lane < NUM_CAND) ? expf(s - m) : 0.f;
        float ssum = e;
        #pragma unroll
        for (int off = 32; off; off >>= 1) ssum += __shfl_xor(ssum, off);
        if (lane < NUM_CAND)
            out[b * NUM_CAND + lane] = e / ssum;
    }
}

extern "C" void kernel_launch(void* const* d_in, const int* in_sizes, int n_in,
                              void* d_out, int out_size, void* d_ws, size_t ws_size,
                              hipStream_t stream) {
    const float* word_emb     = (const float*)d_in[0];
    const float* entity_emb   = (const float*)d_in[1];
    const float* W            = (const float*)d_in[2];
    const float* bias         = (const float*)d_in[3];
    const int*   text_input   = (const int*)d_in[4];
    const int*   entity_input = (const int*)d_in[5];
    // d_in[6] = labels, unused by the forward pass.
    float* out = (float*)d_out;

    ntee_fused<<<BATCH, 256, 0, stream>>>(
        word_emb, entity_emb, W, bias, text_input, entity_input, out);
}